// Round 4
// baseline (568.513 us; speedup 1.0000x reference)
//
#include <hip/hip_runtime.h>
#include <hip/hip_bf16.h>

typedef unsigned short ushort_t;
typedef unsigned int uint_t;

typedef __attribute__((ext_vector_type(8))) short short8;
typedef __attribute__((ext_vector_type(4))) float f32x4;

#define BATCH 512
#define DK    512
#define CTOT  100000
#define CPAD  100032              // CTOT rounded up to 64
#define BNF   64                  // per-block (and per-wave) column tile
#define THRESH_C (-0.8775825618903728f)   // cos(pi - 0.5)
#define MM_C     (0.2397127693021015f)    // sin(0.5)*0.5

// round-to-nearest-even fp32 -> bf16
static __device__ __forceinline__ ushort_t f2bf(float f) {
    union { float f; uint_t u; } v; v.f = f;
    return (ushort_t)((v.u + 0x7FFFu + ((v.u >> 16) & 1u)) >> 16);
}

// ---------------------------------------------------------------------------
// Prep: normalize x rows -> bf16 stored in MFMA-A-fragment-major order:
//   exbF[row_block(32)][ko(16)][lane(64)*8 elems]
//   element (b,k): row_block=b>>4, ko=k>>5, lane=(k>>3&3)*16+(b&15), j=k&7
// Also computes fp32-exact target[b] from cos_lb.
// grid = 512 blocks (one per batch row), 256 threads.
// ---------------------------------------------------------------------------
__global__ __launch_bounds__(256) void arc_prep(
    const float* __restrict__ x, const int* __restrict__ label,
    const float* __restrict__ w, float* __restrict__ target,
    ushort_t* __restrict__ exbF)
{
    const int b = blockIdx.x;
    const int t = threadIdx.x;
    __shared__ float red[8];

    const float2 xv = ((const float2*)(x + (size_t)b * DK))[t];
    float ss = xv.x * xv.x + xv.y * xv.y;
    #pragma unroll
    for (int o = 32; o; o >>= 1) ss += __shfl_xor(ss, o);
    if ((t & 63) == 0) red[t >> 6] = ss;
    __syncthreads();
    const float ssx = red[0] + red[1] + red[2] + red[3];
    const float rnx = 1.0f / sqrtf(ssx);

    {
        const int k = 2 * t;
        const int ko = k >> 5;
        const int qk = (k >> 3) & 3;
        const int kj = k & 7;                       // even
        const size_t F = (size_t)(b >> 4) * 8192 + (size_t)ko * 512
                       + (size_t)qk * 128 + (size_t)(b & 15) * 8 + kj;
        ushort2 e;
        e.x = f2bf(xv.x * rnx);
        e.y = f2bf(xv.y * rnx);
        *(ushort2*)(exbF + F) = e;
    }

    const int lb = label[b];
    const float2 wv = ((const float2*)(w + (size_t)lb * DK))[t];
    float ssw = wv.x * wv.x + wv.y * wv.y;
    float dot = xv.x * wv.x + xv.y * wv.y;
    #pragma unroll
    for (int o = 32; o; o >>= 1) { ssw += __shfl_xor(ssw, o); dot += __shfl_xor(dot, o); }
    __syncthreads();                 // guard red[] reuse
    if ((t & 63) == 0) { red[t >> 6] = ssw; red[4 + (t >> 6)] = dot; }
    __syncthreads();
    if (t == 0) {
        const float sw = red[0] + red[1] + red[2] + red[3];
        const float dt = red[4] + red[5] + red[6] + red[7];
        float cl = dt * rnx / sqrtf(sw);
        cl = fminf(fmaxf(cl, -1.0f), 1.0f);
        const float tg = (cl > THRESH_C) ? cosf(acosf(cl) + 0.5f) : (cl - MM_C);
        target[b] = tg;
    }
}

// ---------------------------------------------------------------------------
// Main: fused GEMM. No LDS, no barriers, no pre-conversion pass.
// 512 threads = 8 waves; wave w owns rows w*64..w*64+63 x all 64 cols
// (acc[4][4]). B-operands are converted fp32 W -> bf16 IN REGISTERS inside
// the K-loop: for fragment (nt,ko), lane (qk,colq) loads
// W[c0+nt*16+colq][ko*32+qk*8 .. +7] (2x float4; the 4 qk-lanes of a colq
// consume exactly one 128B line, so W is read once, fully line-efficient).
// Per-class sumsq accumulates in-lane (each qk covers k%32 in [qk*8,qk*8+8)
// over all ko = 1/4 of the row; shfl_xor 16/32 completes it). W fp32 read
// once (205 MB) replaces the separate wcvt pass (205r + 102w) + wbF reread.
// Stores are PLAIN dwords (not nontemporal): r2/r3 showed NT dword stores
// pin at ~1.9 TB/s with 1.2x write amplification (partial 64B lines bypass
// L2 merging); plain stores let L2 merge adjacent nt-halves into full lines
// (r0/r1 evidence: same epilogue, no NT, amp 1.00-1.10x).
// grid = CPAD/64 = 1563; only the last tile predicates.
// ---------------------------------------------------------------------------
__global__ __launch_bounds__(512, 4) void arc_main_f(
    const ushort_t* __restrict__ exbF, const float* __restrict__ w,
    const int* __restrict__ label, const float* __restrict__ target,
    float* __restrict__ out)
{
    const int t    = threadIdx.x;
    const int lane = t & 63;
    const int wid  = t >> 6;           // 0..7 row-group
    const int tile = blockIdx.x;
    const int c0   = tile * BNF;
    const int colq = lane & 15;
    const int qk   = lane >> 4;

    const ushort_t* abase = exbF + (size_t)(wid * 4) * 8192 + (size_t)lane * 8;

    f32x4 acc[4][4];
    #pragma unroll
    for (int i = 0; i < 4; ++i)
        #pragma unroll
        for (int j = 0; j < 4; ++j)
            acc[i][j] = (f32x4){0.f, 0.f, 0.f, 0.f};

    float ss[4] = {0.f, 0.f, 0.f, 0.f};

#define KLOOP(GUARD)                                                           \
    {                                                                          \
        const float* wl[4];                                                    \
        bool vm[4];                                                            \
        _Pragma("unroll")                                                      \
        for (int nt = 0; nt < 4; ++nt) {                                       \
            const int cls = c0 + nt * 16 + colq;                               \
            vm[nt] = !GUARD || (cls < CTOT);                                   \
            wl[nt] = w + (size_t)(vm[nt] ? cls : 0) * DK + qk * 8;             \
        }                                                                      \
        _Pragma("unroll 2")                                                    \
        for (int ko = 0; ko < 16; ++ko) {                                      \
            short8 bfr[4];                                                     \
            _Pragma("unroll")                                                  \
            for (int nt = 0; nt < 4; ++nt) {                                   \
                const float* wp = wl[nt] + ko * 32;                            \
                float4 q0 = *(const float4*)wp;                                \
                float4 q1 = *(const float4*)(wp + 4);                          \
                if (GUARD && !vm[nt]) {                                        \
                    q0 = make_float4(0.f, 0.f, 0.f, 0.f); q1 = q0;             \
                }                                                              \
                ss[nt] += q0.x * q0.x + q0.y * q0.y + q0.z * q0.z + q0.w * q0.w\
                        + q1.x * q1.x + q1.y * q1.y + q1.z * q1.z + q1.w * q1.w;\
                union { short8 s; uint4 u; } bb;                               \
                bb.u.x = (uint_t)f2bf(q0.x) | ((uint_t)f2bf(q0.y) << 16);      \
                bb.u.y = (uint_t)f2bf(q0.z) | ((uint_t)f2bf(q0.w) << 16);      \
                bb.u.z = (uint_t)f2bf(q1.x) | ((uint_t)f2bf(q1.y) << 16);      \
                bb.u.w = (uint_t)f2bf(q1.z) | ((uint_t)f2bf(q1.w) << 16);      \
                bfr[nt] = bb.s;                                                \
            }                                                                  \
            _Pragma("unroll")                                                  \
            for (int mt = 0; mt < 4; ++mt) {                                   \
                const short8 afr = *(const short8*)(abase + (size_t)mt * 8192  \
                                                    + ko * 512);               \
                _Pragma("unroll")                                              \
                for (int nt = 0; nt < 4; ++nt)                                 \
                    acc[mt][nt] = __builtin_amdgcn_mfma_f32_16x16x32_bf16(     \
                        afr, bfr[nt], acc[mt][nt], 0, 0, 0);                   \
            }                                                                  \
        }                                                                      \
    }

    const bool full = (c0 + BNF <= CTOT);
    if (full) { KLOOP(false) } else { KLOOP(true) }
#undef KLOOP

    // complete per-class sumsq across the 4 qk lane-groups (bits 4,5 of lane)
    float rn[4];
    #pragma unroll
    for (int nt = 0; nt < 4; ++nt) {
        float s = ss[nt];
        s += __shfl_xor(s, 16);
        s += __shfl_xor(s, 32);
        rn[nt] = 1.0f / sqrtf(s);
    }

    const int m0 = wid * 64;

#define EPILOGUE(GUARD)                                                        \
    _Pragma("unroll")                                                          \
    for (int mt = 0; mt < 4; ++mt) {                                           \
        _Pragma("unroll")                                                      \
        for (int rr = 0; rr < 4; ++rr) {                                       \
            const int row = m0 + mt * 16 + qk * 4 + rr;                        \
            const float tg = target[row];                                      \
            const int   lb = label[row];                                       \
            float* orow = out + (size_t)row * CTOT + c0;                       \
            _Pragma("unroll")                                                  \
            for (int nt = 0; nt < 4; ++nt) {                                   \
                const int cc = c0 + nt * 16 + colq;                            \
                if (GUARD && cc >= CTOT) continue;                             \
                const float cosv = acc[mt][nt][rr] * rn[nt];                   \
                const float d  = cosv - tg;                                    \
                const float ts = 1.2f * __expf(d * d * -0.5f);                 \
                const float v  = (cc == lb) ? 64.0f * tg                       \
                                            : 64.0f * (ts * cosv + ts - 1.0f); \
                orow[nt * 16 + colq] = v;                                      \
            }                                                                  \
        }                                                                      \
    }

    if (full) { EPILOGUE(false) } else { EPILOGUE(true) }
#undef EPILOGUE
}

extern "C" void kernel_launch(void* const* d_in, const int* in_sizes, int n_in,
                              void* d_out, int out_size, void* d_ws, size_t ws_size,
                              hipStream_t stream) {
    const float* x     = (const float*)d_in[0];
    const int*   label = (const int*)d_in[1];
    const float* w     = (const float*)d_in[2];
    float* out = (float*)d_out;

    // workspace layout: target (2 KB) + exbF (512 KB)
    float*    target = (float*)d_ws;
    ushort_t* exbF   = (ushort_t*)((char*)d_ws + 2048);

    arc_prep<<<512, 256, 0, stream>>>(x, label, w, target, exbF);
    arc_main_f<<<CPAD / BNF, 512, 0, stream>>>(exbF, w, label, target, out);
}

// Round 5
// 452.210 us; speedup vs baseline: 1.2572x; 1.2572x over previous
//
#include <hip/hip_runtime.h>
#include <hip/hip_bf16.h>

typedef unsigned short ushort_t;
typedef unsigned int uint_t;

typedef __attribute__((ext_vector_type(8))) short short8;
typedef __attribute__((ext_vector_type(4))) float f32x4;

#define BATCH 512
#define DK    512
#define CTOT  100000
#define CPAD  100032              // CTOT rounded up to 64
#define BN    32                  // fallback kernel tile
#define BNF   64                  // fast-path per-block/per-wave column tile
#define THRESH_C (-0.8775825618903728f)   // cos(pi - 0.5)
#define MM_C     (0.2397127693021015f)    // sin(0.5)*0.5

// round-to-nearest-even fp32 -> bf16
static __device__ __forceinline__ ushort_t f2bf(float f) {
    union { float f; uint_t u; } v; v.f = f;
    return (ushort_t)((v.u + 0x7FFFu + ((v.u >> 16) & 1u)) >> 16);
}

// ---------------------------------------------------------------------------
// Prep: normalize x rows -> bf16 stored in MFMA-A-fragment-major order:
//   exbF[row_block(32)][ko(16)][lane(64)*8 elems]
//   element (b,k): row_block=b>>4, ko=k>>5, lane=(k>>3&3)*16+(b&15), j=k&7
// Also computes fp32-exact target[b] from cos_lb.
// grid = 512 blocks (one per batch row), 256 threads.
// ---------------------------------------------------------------------------
__global__ __launch_bounds__(256) void arc_prep(
    const float* __restrict__ x, const int* __restrict__ label,
    const float* __restrict__ w, float* __restrict__ target,
    ushort_t* __restrict__ exbF)
{
    const int b = blockIdx.x;
    const int t = threadIdx.x;
    __shared__ float red[8];

    const float2 xv = ((const float2*)(x + (size_t)b * DK))[t];
    float ss = xv.x * xv.x + xv.y * xv.y;
    #pragma unroll
    for (int o = 32; o; o >>= 1) ss += __shfl_xor(ss, o);
    if ((t & 63) == 0) red[t >> 6] = ss;
    __syncthreads();
    const float ssx = red[0] + red[1] + red[2] + red[3];
    const float rnx = 1.0f / sqrtf(ssx);

    {
        const int k = 2 * t;
        const int ko = k >> 5;
        const int qk = (k >> 3) & 3;
        const int kj = k & 7;                       // even
        const size_t F = (size_t)(b >> 4) * 8192 + (size_t)ko * 512
                       + (size_t)qk * 128 + (size_t)(b & 15) * 8 + kj;
        ushort2 e;
        e.x = f2bf(xv.x * rnx);
        e.y = f2bf(xv.y * rnx);
        *(ushort2*)(exbF + F) = e;
    }

    const int lb = label[b];
    const float2 wv = ((const float2*)(w + (size_t)lb * DK))[t];
    float ssw = wv.x * wv.x + wv.y * wv.y;
    float dot = xv.x * wv.x + xv.y * wv.y;
    #pragma unroll
    for (int o = 32; o; o >>= 1) { ssw += __shfl_xor(ssw, o); dot += __shfl_xor(dot, o); }
    __syncthreads();                 // guard red[] reuse
    if ((t & 63) == 0) { red[t >> 6] = ssw; red[4 + (t >> 6)] = dot; }
    __syncthreads();
    if (t == 0) {
        const float sw = red[0] + red[1] + red[2] + red[3];
        const float dt = red[4] + red[5] + red[6] + red[7];
        float cl = dt * rnx / sqrtf(sw);
        cl = fminf(fmaxf(cl, -1.0f), 1.0f);
        const float tg = (cl > THRESH_C) ? cosf(acosf(cl) + 0.5f) : (cl - MM_C);
        target[b] = tg;
    }
}

// ---------------------------------------------------------------------------
// W convert: one streaming pass fp32 W -> bf16 fragment-major wbF (same
// per-16-row-block fragment formula as exbF) + per-class 1/sqrt(sumsq) fp32.
// Rows >= CTOT (padding up to CPAD) get zero fragments and rnw = 0 so the
// main kernel needs no load predication, only store predication in the one
// tail tile. 16B stores (ushort8). grid = CPAD/16 blocks, 256 threads.
// ---------------------------------------------------------------------------
__global__ __launch_bounds__(256) void arc_wcvt(
    const float* __restrict__ w, ushort_t* __restrict__ wbF,
    float* __restrict__ rnw)
{
    const int rb  = blockIdx.x;        // row-block 0..CPAD/16-1
    const int t   = threadIdx.x;
    const int r   = t >> 4;            // 0..15 local row
    const int c16 = t & 15;
    const int row = rb * 16 + r;
    const bool valid = (row < CTOT);   // block-uniform (CTOT % 16 == 0)
    const float* wrow = w + (size_t)row * DK;
    ushort_t* fbase = wbF + (size_t)rb * 8192 + (size_t)r * 8;

    float ss = 0.0f;
    #pragma unroll
    for (int i = 0; i < 4; ++i) {
        const int c = i * 128 + c16 * 8;           // 8 consecutive floats
        float4 q0 = make_float4(0.f, 0.f, 0.f, 0.f);
        float4 q1 = q0;
        if (valid) {
            q0 = *(const float4*)(wrow + c);
            q1 = *(const float4*)(wrow + c + 4);
        }
        ss += q0.x * q0.x + q0.y * q0.y + q0.z * q0.z + q0.w * q0.w
            + q1.x * q1.x + q1.y * q1.y + q1.z * q1.z + q1.w * q1.w;
        uint4 p;
        p.x = (uint_t)f2bf(q0.x) | ((uint_t)f2bf(q0.y) << 16);
        p.y = (uint_t)f2bf(q0.z) | ((uint_t)f2bf(q0.w) << 16);
        p.z = (uint_t)f2bf(q1.x) | ((uint_t)f2bf(q1.y) << 16);
        p.w = (uint_t)f2bf(q1.z) | ((uint_t)f2bf(q1.w) << 16);
        const int ko = c >> 5;
        const int qk = (c >> 3) & 3;               // j0 = c & 7 == 0 always
        *(uint4*)(fbase + ko * 512 + qk * 128) = p;
    }
    ss += __shfl_xor(ss, 1);
    ss += __shfl_xor(ss, 2);
    ss += __shfl_xor(ss, 4);
    ss += __shfl_xor(ss, 8);
    if (c16 == 0) rnw[row] = valid ? (1.0f / sqrtf(ss)) : 0.0f;
}

// ---------------------------------------------------------------------------
// Main (fast path): pure-dataflow bf16 GEMM + epilogue. No LDS, no barriers.
// 512 threads = 8 waves; wave w owns rows w*64..w*64+63, all 64 cols
// (acc[4][4]): 0.5 loads/MFMA, 16 independent MFMA per 8 loads.
// Stores are PLAIN dwords. Evidence: r2/r3 (NT stores) pinned at
// WRITE/dur = 1.87/1.92 TB/s with 1.22x write amplification -- the NT dword
// path emits partial 64B lines (L2 bypassed, no merging) and the saturated
// store path backpressured every wave (71K-cycle per-wave stall, occupancy-
// independent). r4 measured plain-store amp = 1.07x: L2 merges the adjacent
// 64B halves into full lines.
// grid = CPAD/64 = 1563 tiles; only the last tile predicates stores.
// ---------------------------------------------------------------------------
__global__ __launch_bounds__(512, 4) void arc_main_ff(
    const ushort_t* __restrict__ exbF, const ushort_t* __restrict__ wbF,
    const float* __restrict__ rnw, const int* __restrict__ label,
    const float* __restrict__ target, float* __restrict__ out)
{
    const int t    = threadIdx.x;
    const int lane = t & 63;
    const int wid  = t >> 6;           // 0..7 row-group
    const int tile = blockIdx.x;
    const int c0   = tile * BNF;
    const int colq = lane & 15;
    const int qk   = lane >> 4;

    const ushort_t* abase = exbF + (size_t)(wid * 4) * 8192 + (size_t)lane * 8;
    const ushort_t* bbase = wbF + (size_t)(tile * 4) * 8192 + (size_t)lane * 8;

    f32x4 acc[4][4];
    #pragma unroll
    for (int i = 0; i < 4; ++i)
        #pragma unroll
        for (int j = 0; j < 4; ++j)
            acc[i][j] = (f32x4){0.f, 0.f, 0.f, 0.f};

    #pragma unroll 4
    for (int ko = 0; ko < 16; ++ko) {
        short8 bfr[4];
        #pragma unroll
        for (int nt = 0; nt < 4; ++nt)
            bfr[nt] = *(const short8*)(bbase + (size_t)nt * 8192 + ko * 512);
        #pragma unroll
        for (int mt = 0; mt < 4; ++mt) {
            const short8 afr = *(const short8*)(abase + (size_t)mt * 8192 + ko * 512);
            #pragma unroll
            for (int nt = 0; nt < 4; ++nt)
                acc[mt][nt] = __builtin_amdgcn_mfma_f32_16x16x32_bf16(afr, bfr[nt], acc[mt][nt], 0, 0, 0);
        }
    }

    float rn[4];
    #pragma unroll
    for (int nt = 0; nt < 4; ++nt) rn[nt] = rnw[c0 + nt * 16 + colq];

    const int m0 = wid * 64;

#define EPILOGUE(GUARD)                                                        \
    _Pragma("unroll")                                                          \
    for (int mt = 0; mt < 4; ++mt) {                                           \
        _Pragma("unroll")                                                      \
        for (int rr = 0; rr < 4; ++rr) {                                       \
            const int row = m0 + mt * 16 + qk * 4 + rr;                        \
            const float tg = target[row];                                      \
            const int   lb = label[row];                                       \
            float* orow = out + (size_t)row * CTOT + c0;                       \
            _Pragma("unroll")                                                  \
            for (int nt = 0; nt < 4; ++nt) {                                   \
                const int cc = c0 + nt * 16 + colq;                            \
                if (GUARD && cc >= CTOT) continue;                             \
                const float cosv = acc[mt][nt][rr] * rn[nt];                   \
                const float d  = cosv - tg;                                    \
                const float ts = 1.2f * __expf(d * d * -0.5f);                 \
                const float v  = (cc == lb) ? 64.0f * tg                       \
                                            : 64.0f * (ts * cosv + ts - 1.0f); \
                orow[nt * 16 + colq] = v;                                      \
            }                                                                  \
        }                                                                      \
    }

    if (c0 + BNF <= CTOT) {            // uniform: all but the last tile
        EPILOGUE(false)
    } else {
        EPILOGUE(true)
    }
#undef EPILOGUE
}

// ---------------------------------------------------------------------------
// Fallback (verified round-1 kernel) used if workspace can't hold wbF.
// ---------------------------------------------------------------------------
__global__ __launch_bounds__(512, 8) void arc_main_lds(
    const ushort_t* __restrict__ exbF, const float* __restrict__ w,
    const int* __restrict__ label, const float* __restrict__ target,
    float* __restrict__ out)
{
    __shared__ ushort_t Bs[BN * DK];   // 32 KB

    const int t    = threadIdx.x;
    const int lane = t & 63;
    const int wid  = t >> 6;
    const int c0   = blockIdx.x * BN;

    const int br  = t >> 4;
    const int bj  = t & 15;
    const float* wrow = w + (size_t)(c0 + br) * DK;
    const int s3 = br & 7;
    float bsq = 0.0f;
    #pragma unroll
    for (int i = 0; i < 8; ++i) {
        const int c = i * 64 + bj * 4;
        const float4 q = *(const float4*)(wrow + c);
        bsq += q.x * q.x + q.y * q.y + q.z * q.z + q.w * q.w;
        uint2 p;
        p.x = (uint_t)f2bf(q.x) | ((uint_t)f2bf(q.y) << 16);
        p.y = (uint_t)f2bf(q.z) | ((uint_t)f2bf(q.w) << 16);
        const int k16 = c >> 3;
        const int sw  = k16 ^ s3;
        *(uint2*)&Bs[br * DK + sw * 8 + (bj & 1) * 4] = p;
    }
    bsq += __shfl_xor(bsq, 1);
    bsq += __shfl_xor(bsq, 2);
    bsq += __shfl_xor(bsq, 4);
    bsq += __shfl_xor(bsq, 8);
    __syncthreads();

    const int m0   = wid * 64;
    const int colq = lane & 15;
    const int qk   = lane >> 4;
    const int bs3  = colq & 7;
    const ushort_t* abase = exbF + (size_t)(wid * 4) * 8192 + (size_t)lane * 8;

    f32x4 acc[4][2];
    #pragma unroll
    for (int i = 0; i < 4; ++i)
        #pragma unroll
        for (int j = 0; j < 2; ++j)
            acc[i][j] = (f32x4){0.f, 0.f, 0.f, 0.f};

    #pragma unroll 2
    for (int ko = 0; ko < 16; ++ko) {
        short8 bfr[2];
        #pragma unroll
        for (int nt = 0; nt < 2; ++nt) {
            const int idx = (nt * 16 + colq) * DK + (((ko << 2) | qk) ^ bs3) * 8;
            bfr[nt] = *(const short8*)&Bs[idx];
        }
        #pragma unroll
        for (int mt = 0; mt < 4; ++mt) {
            const short8 afr = *(const short8*)(abase + (size_t)mt * 8192 + ko * 512);
            acc[mt][0] = __builtin_amdgcn_mfma_f32_16x16x32_bf16(afr, bfr[0], acc[mt][0], 0, 0, 0);
            acc[mt][1] = __builtin_amdgcn_mfma_f32_16x16x32_bf16(afr, bfr[1], acc[mt][1], 0, 0, 0);
        }
    }

    __syncthreads();
    if (bj == 0) ((float*)Bs)[br] = 1.0f / sqrtf(bsq);
    __syncthreads();
    float rn[2];
    rn[0] = ((float*)Bs)[colq];
    rn[1] = ((float*)Bs)[16 + colq];

    #pragma unroll
    for (int mt = 0; mt < 4; ++mt) {
        #pragma unroll
        for (int rr = 0; rr < 4; ++rr) {
            const int row = m0 + mt * 16 + qk * 4 + rr;
            const float tg = target[row];
            const int   lb = label[row];
            float* orow = out + (size_t)row * CTOT + c0;
            #pragma unroll
            for (int nt = 0; nt < 2; ++nt) {
                const int cc = c0 + nt * 16 + colq;
                const float cosv = acc[mt][nt][rr] * rn[nt];
                const float d  = cosv - tg;
                const float ts = 1.2f * __expf(d * d * -0.5f);
                const float v  = (cc == lb) ? 64.0f * tg
                                            : 64.0f * (ts * cosv + ts - 1.0f);
                orow[nt * 16 + colq] = v;
            }
        }
    }
}

extern "C" void kernel_launch(void* const* d_in, const int* in_sizes, int n_in,
                              void* d_out, int out_size, void* d_ws, size_t ws_size,
                              hipStream_t stream) {
    const float* x     = (const float*)d_in[0];
    const int*   label = (const int*)d_in[1];
    const float* w     = (const float*)d_in[2];
    float* out = (float*)d_out;

    // workspace layout
    float*    target = (float*)d_ws;                          // 2 KB
    ushort_t* exbF   = (ushort_t*)((char*)d_ws + 2048);       // 512 KB
    float*    rnw    = (float*)((char*)d_ws + 526336);        // CPAD*4 = 400128 B
    ushort_t* wbF    = (ushort_t*)((char*)d_ws + 926720);     // CPAD*512*2
    const size_t WS_NEED = 926720 + (size_t)CPAD * DK * 2;    // 103,359,488

    arc_prep<<<512, 256, 0, stream>>>(x, label, w, target, exbF);

    if (ws_size >= WS_NEED) {
        arc_wcvt<<<CPAD / 16, 256, 0, stream>>>(w, wbF, rnw);
        arc_main_ff<<<CPAD / BNF, 512, 0, stream>>>(exbF, wbF, rnw, label, target, out);
    } else {
        arc_main_lds<<<CTOT / BN, 512, 0, stream>>>(exbF, w, label, target, out);
    }
}

// Round 7
// 416.861 us; speedup vs baseline: 1.3638x; 1.0848x over previous
//
#include <hip/hip_runtime.h>
#include <hip/hip_bf16.h>

typedef unsigned short ushort_t;
typedef unsigned int uint_t;

typedef __attribute__((ext_vector_type(8))) short short8;
typedef __attribute__((ext_vector_type(4))) float f32x4;

#define BATCH 512
#define DK    512
#define CTOT  100000
#define CPAD  100032              // CTOT rounded up to 64
#define BN    32                  // fallback kernel tile
#define BNF   64                  // fast-path per-block column tile
#define THRESH_C (-0.8775825618903728f)   // cos(pi - 0.5)
#define MM_C     (0.2397127693021015f)    // sin(0.5)*0.5

// round-to-nearest-even fp32 -> bf16
static __device__ __forceinline__ ushort_t f2bf(float f) {
    union { float f; uint_t u; } v; v.f = f;
    return (ushort_t)((v.u + 0x7FFFu + ((v.u >> 16) & 1u)) >> 16);
}

// ---------------------------------------------------------------------------
// Prep: normalize x rows -> bf16 stored in MFMA-A-fragment-major order:
//   exbF[row_block(32)][ko(16)][lane(64)*8 elems]
//   element (b,k): row_block=b>>4, ko=k>>5, lane=(k>>3&3)*16+(b&15), j=k&7
// Also computes fp32-exact target[b] from cos_lb.
// grid = 512 blocks (one per batch row), 256 threads.
// ---------------------------------------------------------------------------
__global__ __launch_bounds__(256) void arc_prep(
    const float* __restrict__ x, const int* __restrict__ label,
    const float* __restrict__ w, float* __restrict__ target,
    ushort_t* __restrict__ exbF)
{
    const int b = blockIdx.x;
    const int t = threadIdx.x;
    __shared__ float red[8];

    const float2 xv = ((const float2*)(x + (size_t)b * DK))[t];
    float ss = xv.x * xv.x + xv.y * xv.y;
    #pragma unroll
    for (int o = 32; o; o >>= 1) ss += __shfl_xor(ss, o);
    if ((t & 63) == 0) red[t >> 6] = ss;
    __syncthreads();
    const float ssx = red[0] + red[1] + red[2] + red[3];
    const float rnx = 1.0f / sqrtf(ssx);

    {
        const int k = 2 * t;
        const int ko = k >> 5;
        const int qk = (k >> 3) & 3;
        const int kj = k & 7;                       // even
        const size_t F = (size_t)(b >> 4) * 8192 + (size_t)ko * 512
                       + (size_t)qk * 128 + (size_t)(b & 15) * 8 + kj;
        ushort2 e;
        e.x = f2bf(xv.x * rnx);
        e.y = f2bf(xv.y * rnx);
        *(ushort2*)(exbF + F) = e;
    }

    const int lb = label[b];
    const float2 wv = ((const float2*)(w + (size_t)lb * DK))[t];
    float ssw = wv.x * wv.x + wv.y * wv.y;
    float dot = xv.x * wv.x + xv.y * wv.y;
    #pragma unroll
    for (int o = 32; o; o >>= 1) { ssw += __shfl_xor(ssw, o); dot += __shfl_xor(dot, o); }
    __syncthreads();                 // guard red[] reuse
    if ((t & 63) == 0) { red[t >> 6] = ssw; red[4 + (t >> 6)] = dot; }
    __syncthreads();
    if (t == 0) {
        const float sw = red[0] + red[1] + red[2] + red[3];
        const float dt = red[4] + red[5] + red[6] + red[7];
        float cl = dt * rnx / sqrtf(sw);
        cl = fminf(fmaxf(cl, -1.0f), 1.0f);
        const float tg = (cl > THRESH_C) ? cosf(acosf(cl) + 0.5f) : (cl - MM_C);
        target[b] = tg;
    }
}

// ---------------------------------------------------------------------------
// W convert: one streaming pass fp32 W -> bf16 fragment-major wbF (same
// per-16-row-block fragment formula as exbF) + per-class 1/sqrt(sumsq) fp32.
// Rows >= CTOT (padding up to CPAD) get zero fragments and rnw = 0.
// grid = CPAD/16 blocks, 256 threads.
// ---------------------------------------------------------------------------
__global__ __launch_bounds__(256) void arc_wcvt(
    const float* __restrict__ w, ushort_t* __restrict__ wbF,
    float* __restrict__ rnw)
{
    const int rb  = blockIdx.x;        // row-block 0..CPAD/16-1
    const int t   = threadIdx.x;
    const int r   = t >> 4;            // 0..15 local row
    const int c16 = t & 15;
    const int row = rb * 16 + r;
    const bool valid = (row < CTOT);   // block-uniform (CTOT % 16 == 0)
    const float* wrow = w + (size_t)row * DK;
    ushort_t* fbase = wbF + (size_t)rb * 8192 + (size_t)r * 8;

    float ss = 0.0f;
    #pragma unroll
    for (int i = 0; i < 4; ++i) {
        const int c = i * 128 + c16 * 8;           // 8 consecutive floats
        float4 q0 = make_float4(0.f, 0.f, 0.f, 0.f);
        float4 q1 = q0;
        if (valid) {
            q0 = *(const float4*)(wrow + c);
            q1 = *(const float4*)(wrow + c + 4);
        }
        ss += q0.x * q0.x + q0.y * q0.y + q0.z * q0.z + q0.w * q0.w
            + q1.x * q1.x + q1.y * q1.y + q1.z * q1.z + q1.w * q1.w;
        uint4 p;
        p.x = (uint_t)f2bf(q0.x) | ((uint_t)f2bf(q0.y) << 16);
        p.y = (uint_t)f2bf(q0.z) | ((uint_t)f2bf(q0.w) << 16);
        p.z = (uint_t)f2bf(q1.x) | ((uint_t)f2bf(q1.y) << 16);
        p.w = (uint_t)f2bf(q1.z) | ((uint_t)f2bf(q1.w) << 16);
        const int ko = c >> 5;
        const int qk = (c >> 3) & 3;               // j0 = c & 7 == 0 always
        *(uint4*)(fbase + ko * 512 + qk * 128) = p;
    }
    ss += __shfl_xor(ss, 1);
    ss += __shfl_xor(ss, 2);
    ss += __shfl_xor(ss, 4);
    ss += __shfl_xor(ss, 8);
    if (c16 == 0) rnw[row] = valid ? (1.0f / sqrtf(ss)) : 0.0f;
}

// ---------------------------------------------------------------------------
// Main (fast path): LDS-staged bf16 GEMM + transposed full-line NT epilogue.
// Per block: stage the 64 KB fragment-major B tile (wbF) into LDS ONCE with
// coalesced uint4 copies (linear layout - no conversion, one barrier), then a
// barrier-free K-loop: A-frags from L2-hot exbF (global), B-frags via
// ds_read_b128 (offsets fold into the 16-bit LDS immediate). Evidence: the
// r2-r5 global-B loop was latency-pinned (~72K cyc/wave regardless of config);
// LDS-B cuts per-ko operand latency ~5x and B's L2 traffic 8x.
// Epilogue: after a barrier Bs is dead -> per-wave 16x67 f32 scratch; write
// logits, lgkmcnt(0), read back transposed so each lane stores f32x4 of 4
// consecutive cols -> NT dwordx4 = full 64B lines. Evidence: NT dword stores
// capped at WRITE/1.9 TB/s with 1.22x amp (r2/r3); plain dwords fixed amp but
// polluted L2 and lost 19us (r5). Full-line NT keeps L2 clean AND amp ~1.0.
// grid = CPAD/64 = 1563; only the last tile predicates (CTOT % 4 == 0).
// ---------------------------------------------------------------------------
__global__ __launch_bounds__(512, 4) void arc_main_ff(
    const ushort_t* __restrict__ exbF, const ushort_t* __restrict__ wbF,
    const float* __restrict__ rnw, const int* __restrict__ label,
    const float* __restrict__ target, float* __restrict__ out)
{
    __shared__ ushort_t Bs[4 * 8192];  // 64 KB: B tile, then f32 scratch

    const int t    = threadIdx.x;
    const int lane = t & 63;
    const int wid  = t >> 6;           // 0..7 row-group
    const int tile = blockIdx.x;
    const int c0   = tile * BNF;
    const int colq = lane & 15;
    const int qk   = lane >> 4;

    // ---- stage B tile: 64 KB linear copy, 8 x uint4 per thread, coalesced
    {
        const uint4* gB = (const uint4*)(wbF + (size_t)tile * 4 * 8192);
        uint4* lB = (uint4*)Bs;
        #pragma unroll
        for (int i = 0; i < 8; ++i)
            lB[i * 512 + t] = gB[i * 512 + t];
    }

    const ushort_t* abase = exbF + (size_t)(wid * 4) * 8192 + (size_t)lane * 8;

    f32x4 acc[4][4];
    #pragma unroll
    for (int i = 0; i < 4; ++i)
        #pragma unroll
        for (int j = 0; j < 4; ++j)
            acc[i][j] = (f32x4){0.f, 0.f, 0.f, 0.f};

    __syncthreads();                   // B tile visible (drains vmcnt+lgkmcnt)

    // ---- barrier-free K loop: A from global (L2-hot), B from LDS
    const ushort_t* bbase = Bs + (size_t)lane * 8;
    #pragma unroll 2
    for (int ko = 0; ko < 16; ++ko) {
        short8 bfr[4], afr[4];
        #pragma unroll
        for (int nt = 0; nt < 4; ++nt)
            bfr[nt] = *(const short8*)(bbase + nt * 8192 + ko * 512);
        #pragma unroll
        for (int mt = 0; mt < 4; ++mt)
            afr[mt] = *(const short8*)(abase + (size_t)mt * 8192 + ko * 512);
        #pragma unroll
        for (int mt = 0; mt < 4; ++mt)
            #pragma unroll
            for (int nt = 0; nt < 4; ++nt)
                acc[mt][nt] = __builtin_amdgcn_mfma_f32_16x16x32_bf16(
                    afr[mt], bfr[nt], acc[mt][nt], 0, 0, 0);
    }

    float rn[4];
    #pragma unroll
    for (int nt = 0; nt < 4; ++nt) rn[nt] = rnw[c0 + nt * 16 + colq];

    __syncthreads();                   // all waves done with B -> reuse Bs

    // per-wave 16x67 f32 scratch (4288 B; 8 waves = 33.5 KB <= 64 KB)
    float* Ts = (float*)Bs + wid * (16 * 67);

    const int  m0   = wid * 64;
    const bool full = (c0 + BNF <= CTOT);

    #pragma unroll
    for (int mt = 0; mt < 4; ++mt) {
        // compute logits for this 16x64 sub-tile, scatter to scratch
        #pragma unroll
        for (int rr = 0; rr < 4; ++rr) {
            const int row = m0 + mt * 16 + qk * 4 + rr;
            const float tg = target[row];
            const int   lb = label[row];
            #pragma unroll
            for (int nt = 0; nt < 4; ++nt) {
                const int cc = c0 + nt * 16 + colq;
                const float cosv = acc[mt][nt][rr] * rn[nt];
                const float d  = cosv - tg;
                const float ts = 1.2f * __expf(d * d * -0.5f);
                const float v  = (cc == lb) ? 64.0f * tg
                                            : 64.0f * (ts * cosv + ts - 1.0f);
                Ts[(qk * 4 + rr) * 67 + nt * 16 + colq] = v;
            }
        }
        // lane-crossing LDS exchange within the wave: force write->read order
        asm volatile("s_waitcnt lgkmcnt(0)" ::: "memory");

        // read back transposed: lane handles rows i*4+qk, cols 4*colq..+3
        #pragma unroll
        for (int i = 0; i < 4; ++i) {
            const int r16 = i * 4 + qk;
            const int row = m0 + mt * 16 + r16;
            const int cc4 = 4 * colq;
            f32x4 v;
            v.x = Ts[r16 * 67 + cc4 + 0];
            v.y = Ts[r16 * 67 + cc4 + 1];
            v.z = Ts[r16 * 67 + cc4 + 2];
            v.w = Ts[r16 * 67 + cc4 + 3];
            if (full || (c0 + cc4 < CTOT))
                __builtin_nontemporal_store(
                    v, (f32x4*)(out + (size_t)row * CTOT + c0 + cc4));
        }
        // guard scratch reuse: reads of mt must complete before mt+1 writes
        asm volatile("s_waitcnt lgkmcnt(0)" ::: "memory");
    }
}

// ---------------------------------------------------------------------------
// Fallback (verified round-1 kernel) used if workspace can't hold wbF.
// ---------------------------------------------------------------------------
__global__ __launch_bounds__(512, 8) void arc_main_lds(
    const ushort_t* __restrict__ exbF, const float* __restrict__ w,
    const int* __restrict__ label, const float* __restrict__ target,
    float* __restrict__ out)
{
    __shared__ ushort_t Bs[BN * DK];   // 32 KB

    const int t    = threadIdx.x;
    const int lane = t & 63;
    const int wid  = t >> 6;
    const int c0   = blockIdx.x * BN;

    const int br  = t >> 4;
    const int bj  = t & 15;
    const float* wrow = w + (size_t)(c0 + br) * DK;
    const int s3 = br & 7;
    float bsq = 0.0f;
    #pragma unroll
    for (int i = 0; i < 8; ++i) {
        const int c = i * 64 + bj * 4;
        const float4 q = *(const float4*)(wrow + c);
        bsq += q.x * q.x + q.y * q.y + q.z * q.z + q.w * q.w;
        uint2 p;
        p.x = (uint_t)f2bf(q.x) | ((uint_t)f2bf(q.y) << 16);
        p.y = (uint_t)f2bf(q.z) | ((uint_t)f2bf(q.w) << 16);
        const int k16 = c >> 3;
        const int sw  = k16 ^ s3;
        *(uint2*)&Bs[br * DK + sw * 8 + (bj & 1) * 4] = p;
    }
    bsq += __shfl_xor(bsq, 1);
    bsq += __shfl_xor(bsq, 2);
    bsq += __shfl_xor(bsq, 4);
    bsq += __shfl_xor(bsq, 8);
    __syncthreads();

    const int m0   = wid * 64;
    const int colq = lane & 15;
    const int qk   = lane >> 4;
    const int bs3  = colq & 7;
    const ushort_t* abase = exbF + (size_t)(wid * 4) * 8192 + (size_t)lane * 8;

    f32x4 acc[4][2];
    #pragma unroll
    for (int i = 0; i < 4; ++i)
        #pragma unroll
        for (int j = 0; j < 2; ++j)
            acc[i][j] = (f32x4){0.f, 0.f, 0.f, 0.f};

    #pragma unroll 2
    for (int ko = 0; ko < 16; ++ko) {
        short8 bfr[2];
        #pragma unroll
        for (int nt = 0; nt < 2; ++nt) {
            const int idx = (nt * 16 + colq) * DK + (((ko << 2) | qk) ^ bs3) * 8;
            bfr[nt] = *(const short8*)&Bs[idx];
        }
        #pragma unroll
        for (int mt = 0; mt < 4; ++mt) {
            const short8 afr = *(const short8*)(abase + (size_t)mt * 8192 + ko * 512);
            acc[mt][0] = __builtin_amdgcn_mfma_f32_16x16x32_bf16(afr, bfr[0], acc[mt][0], 0, 0, 0);
            acc[mt][1] = __builtin_amdgcn_mfma_f32_16x16x32_bf16(afr, bfr[1], acc[mt][1], 0, 0, 0);
        }
    }

    __syncthreads();
    if (bj == 0) ((float*)Bs)[br] = 1.0f / sqrtf(bsq);
    __syncthreads();
    float rn[2];
    rn[0] = ((float*)Bs)[colq];
    rn[1] = ((float*)Bs)[16 + colq];

    #pragma unroll
    for (int mt = 0; mt < 4; ++mt) {
        #pragma unroll
        for (int rr = 0; rr < 4; ++rr) {
            const int row = m0 + mt * 16 + qk * 4 + rr;
            const float tg = target[row];
            const int   lb = label[row];
            float* orow = out + (size_t)row * CTOT + c0;
            #pragma unroll
            for (int nt = 0; nt < 2; ++nt) {
                const int cc = c0 + nt * 16 + colq;
                const float cosv = acc[mt][nt][rr] * rn[nt];
                const float d  = cosv - tg;
                const float ts = 1.2f * __expf(d * d * -0.5f);
                const float v  = (cc == lb) ? 64.0f * tg
                                            : 64.0f * (ts * cosv + ts - 1.0f);
                orow[nt * 16 + colq] = v;
            }
        }
    }
}

extern "C" void kernel_launch(void* const* d_in, const int* in_sizes, int n_in,
                              void* d_out, int out_size, void* d_ws, size_t ws_size,
                              hipStream_t stream) {
    const float* x     = (const float*)d_in[0];
    const int*   label = (const int*)d_in[1];
    const float* w     = (const float*)d_in[2];
    float* out = (float*)d_out;

    // workspace layout
    float*    target = (float*)d_ws;                          // 2 KB
    ushort_t* exbF   = (ushort_t*)((char*)d_ws + 2048);       // 512 KB
    float*    rnw    = (float*)((char*)d_ws + 526336);        // CPAD*4 = 400128 B
    ushort_t* wbF    = (ushort_t*)((char*)d_ws + 926720);     // CPAD*512*2
    const size_t WS_NEED = 926720 + (size_t)CPAD * DK * 2;    // 103,359,488

    arc_prep<<<512, 256, 0, stream>>>(x, label, w, target, exbF);

    if (ws_size >= WS_NEED) {
        arc_wcvt<<<CPAD / 16, 256, 0, stream>>>(w, wbF, rnw);
        arc_main_ff<<<CPAD / BNF, 512, 0, stream>>>(exbF, wbF, rnw, label, target, out);
    } else {
        arc_main_lds<<<CTOT / BN, 512, 0, stream>>>(exbF, w, label, target, out);
    }
}

// Round 9
// 393.927 us; speedup vs baseline: 1.4432x; 1.0582x over previous
//
#include <hip/hip_runtime.h>
#include <hip/hip_bf16.h>

typedef unsigned short ushort_t;
typedef unsigned int uint_t;

typedef __attribute__((ext_vector_type(8))) short short8;
typedef __attribute__((ext_vector_type(4))) float f32x4;

#define BATCH 512
#define DK    512
#define CTOT  100000
#define CPAD  100032              // CTOT rounded up to 64
#define BNF   64                  // per-block column tile
#define THRESH_C (-0.8775825618903728f)   // cos(pi - 0.5)
#define MM_C     (0.2397127693021015f)    // sin(0.5)*0.5

// round-to-nearest-even fp32 -> bf16
static __device__ __forceinline__ ushort_t f2bf(float f) {
    union { float f; uint_t u; } v; v.f = f;
    return (ushort_t)((v.u + 0x7FFFu + ((v.u >> 16) & 1u)) >> 16);
}

// ---------------------------------------------------------------------------
// Prep: normalize x rows -> bf16 stored in MFMA-A-fragment-major order:
//   exbF[row_block(32)][ko(16)][lane(64)*8 elems]
//   element (b,k): row_block=b>>4, ko=k>>5, lane=(k>>3&3)*16+(b&15), j=k&7
// Also computes fp32-exact target[b] from cos_lb.
// grid = 512 blocks (one per batch row), 256 threads.
// ---------------------------------------------------------------------------
__global__ __launch_bounds__(256) void arc_prep(
    const float* __restrict__ x, const int* __restrict__ label,
    const float* __restrict__ w, float* __restrict__ target,
    ushort_t* __restrict__ exbF)
{
    const int b = blockIdx.x;
    const int t = threadIdx.x;
    __shared__ float red[8];

    const float2 xv = ((const float2*)(x + (size_t)b * DK))[t];
    float ss = xv.x * xv.x + xv.y * xv.y;
    #pragma unroll
    for (int o = 32; o; o >>= 1) ss += __shfl_xor(ss, o);
    if ((t & 63) == 0) red[t >> 6] = ss;
    __syncthreads();
    const float ssx = red[0] + red[1] + red[2] + red[3];
    const float rnx = 1.0f / sqrtf(ssx);

    {
        const int k = 2 * t;
        const int ko = k >> 5;
        const int qk = (k >> 3) & 3;
        const int kj = k & 7;                       // even
        const size_t F = (size_t)(b >> 4) * 8192 + (size_t)ko * 512
                       + (size_t)qk * 128 + (size_t)(b & 15) * 8 + kj;
        ushort2 e;
        e.x = f2bf(xv.x * rnx);
        e.y = f2bf(xv.y * rnx);
        *(ushort2*)(exbF + F) = e;
    }

    const int lb = label[b];
    const float2 wv = ((const float2*)(w + (size_t)lb * DK))[t];
    float ssw = wv.x * wv.x + wv.y * wv.y;
    float dot = xv.x * wv.x + xv.y * wv.y;
    #pragma unroll
    for (int o = 32; o; o >>= 1) { ssw += __shfl_xor(ssw, o); dot += __shfl_xor(dot, o); }
    __syncthreads();                 // guard red[] reuse
    if ((t & 63) == 0) { red[t >> 6] = ssw; red[4 + (t >> 6)] = dot; }
    __syncthreads();
    if (t == 0) {
        const float sw = red[0] + red[1] + red[2] + red[3];
        const float dt = red[4] + red[5] + red[6] + red[7];
        float cl = dt * rnx / sqrtf(sw);
        cl = fminf(fmaxf(cl, -1.0f), 1.0f);
        const float tg = (cl > THRESH_C) ? cosf(acosf(cl) + 0.5f) : (cl - MM_C);
        target[b] = tg;
    }
}

// ---------------------------------------------------------------------------
// Fused main: stage-and-convert W fp32 -> bf16 LDS fragment tile (replacing
// the r7 wcvt pre-pass: wbF had ZERO reuse -- 205r+102w in wcvt + 102r here
// was 204 MB of pure HBM waste), then the verified r7 K-loop + transposed
// full-line NT epilogue.
//
// Staging: thread t, iter i writes LDS ushort off i*4096 + t*8 (linear ->
// conflict-free ds_write_b128). Inverting the fragment formula: that dest
// holds row c0 + (i>>1)*16 + (t&15), k = [(i&1)*8+wid]*32 + qk*8 .. +8 ->
// src = 8 consecutive fp32 (2x dwordx4, NT: each W line is consumed exactly
// once, by 4 qk-lanes of one wave -- don't pollute L2/exbF). Per-class fp32
// sumsq: per-lane partials over (rb) -> shfl_xor 16/32 sums the qk lanes ->
// rsum[wid][row]; after the barrier 64 threads fold 8 wave-partials and
// overwrite rsum[0..63] with 1/sqrt -> epilogue reads it post-sync2.
//
// K-loop (r7, verified): barrier-free, A-frags from L2-hot exbF, B via
// ds_read_b128, 16 ko x 16 MFMA. Epilogue (r7, verified): per-wave 16x67
// f32 scratch in dead Bs; transposed read-back -> NT f32x4 = full 64B lines
// (NT dword scatter = 1.22x amp @1.9TB/s cap r2/r3; plain = L2 pollution r5).
// grid = CPAD/64 = 1563; only the last tile predicates (CTOT % 4 == 0).
// ---------------------------------------------------------------------------
__global__ __launch_bounds__(512, 4) void arc_fused(
    const ushort_t* __restrict__ exbF, const float* __restrict__ w,
    const int* __restrict__ label, const float* __restrict__ target,
    float* __restrict__ out)
{
    __shared__ ushort_t Bs[4 * 8192];  // 64 KB: B tile, then f32 scratch
    __shared__ float    rsum[8 * 64];  // per-wave sumsq partials; row0 -> rn

    const int t    = threadIdx.x;
    const int lane = t & 63;
    const int wid  = t >> 6;           // 0..7 row-group / ko-group
    const int tile = blockIdx.x;
    const int c0   = tile * BNF;
    const int colq = lane & 15;
    const int qk   = lane >> 4;

    // ---- stage + convert W tile (64 rows x 512) into fragment-major LDS
    {
        float ssr[4] = {0.f, 0.f, 0.f, 0.f};
        #pragma unroll
        for (int i = 0; i < 8; ++i) {
            const int rb  = i >> 1;
            const int ko  = (i & 1) * 8 + wid;
            const int row = c0 + rb * 16 + colq;       // colq == t&15 here
            const float* src = w + (size_t)row * DK + ko * 32 + qk * 8;
            f32x4 q0 = (f32x4){0.f, 0.f, 0.f, 0.f};
            f32x4 q1 = q0;
            if (row < CTOT) {
                q0 = __builtin_nontemporal_load((const f32x4*)src);
                q1 = __builtin_nontemporal_load((const f32x4*)(src + 4));
            }
            ssr[rb] += q0.x * q0.x + q0.y * q0.y + q0.z * q0.z + q0.w * q0.w
                     + q1.x * q1.x + q1.y * q1.y + q1.z * q1.z + q1.w * q1.w;
            uint4 p;
            p.x = (uint_t)f2bf(q0.x) | ((uint_t)f2bf(q0.y) << 16);
            p.y = (uint_t)f2bf(q0.z) | ((uint_t)f2bf(q0.w) << 16);
            p.z = (uint_t)f2bf(q1.x) | ((uint_t)f2bf(q1.y) << 16);
            p.w = (uint_t)f2bf(q1.z) | ((uint_t)f2bf(q1.w) << 16);
            *(uint4*)&Bs[i * 4096 + t * 8] = p;
        }
        // sum the 4 qk lane-groups (lane bits 4,5)
        #pragma unroll
        for (int rb = 0; rb < 4; ++rb) {
            ssr[rb] += __shfl_xor(ssr[rb], 16);
            ssr[rb] += __shfl_xor(ssr[rb], 32);
        }
        if (lane < 16) {
            #pragma unroll
            for (int rb = 0; rb < 4; ++rb)
                rsum[wid * 64 + rb * 16 + lane] = ssr[rb];
        }
    }

    __syncthreads();                   // B tile + rsum partials visible

    // fold 8 wave-partials -> inverse norms in rsum[0..63] (read post-sync2)
    if (t < 64) {
        float s = 0.f;
        #pragma unroll
        for (int wv = 0; wv < 8; ++wv) s += rsum[wv * 64 + t];
        rsum[t] = (c0 + t < CTOT) ? (1.0f / sqrtf(s)) : 0.0f;
    }

    const ushort_t* abase = exbF + (size_t)(wid * 4) * 8192 + (size_t)lane * 8;

    f32x4 acc[4][4];
    #pragma unroll
    for (int i = 0; i < 4; ++i)
        #pragma unroll
        for (int j = 0; j < 4; ++j)
            acc[i][j] = (f32x4){0.f, 0.f, 0.f, 0.f};

    // ---- barrier-free K loop: A from global (L2-hot), B from LDS
    const ushort_t* bbase = Bs + (size_t)lane * 8;
    #pragma unroll 2
    for (int ko = 0; ko < 16; ++ko) {
        short8 bfr[4], afr[4];
        #pragma unroll
        for (int nt = 0; nt < 4; ++nt)
            bfr[nt] = *(const short8*)(bbase + nt * 8192 + ko * 512);
        #pragma unroll
        for (int mt = 0; mt < 4; ++mt)
            afr[mt] = *(const short8*)(abase + (size_t)mt * 8192 + ko * 512);
        #pragma unroll
        for (int mt = 0; mt < 4; ++mt)
            #pragma unroll
            for (int nt = 0; nt < 4; ++nt)
                acc[mt][nt] = __builtin_amdgcn_mfma_f32_16x16x32_bf16(
                    afr[mt], bfr[nt], acc[mt][nt], 0, 0, 0);
    }

    __syncthreads();                   // B dead; rn ready; scratch reuse OK

    float rn[4];
    #pragma unroll
    for (int nt = 0; nt < 4; ++nt) rn[nt] = rsum[nt * 16 + colq];

    // per-wave 16x67 f32 scratch (4288 B; 8 waves = 33.5 KB <= 64 KB)
    float* Ts = (float*)Bs + wid * (16 * 67);

    const int  m0   = wid * 64;
    const bool full = (c0 + BNF <= CTOT);

    #pragma unroll
    for (int mt = 0; mt < 4; ++mt) {
        // compute logits for this 16x64 sub-tile, scatter to scratch
        #pragma unroll
        for (int rr = 0; rr < 4; ++rr) {
            const int row = m0 + mt * 16 + qk * 4 + rr;
            const float tg = target[row];
            const int   lb = label[row];
            #pragma unroll
            for (int nt = 0; nt < 4; ++nt) {
                const int cc = c0 + nt * 16 + colq;
                const float cosv = acc[mt][nt][rr] * rn[nt];
                const float d  = cosv - tg;
                const float ts = 1.2f * __expf(d * d * -0.5f);
                const float v  = (cc == lb) ? 64.0f * tg
                                            : 64.0f * (ts * cosv + ts - 1.0f);
                Ts[(qk * 4 + rr) * 67 + nt * 16 + colq] = v;
            }
        }
        // lane-crossing LDS exchange within the wave: force write->read order
        asm volatile("s_waitcnt lgkmcnt(0)" ::: "memory");

        // read back transposed: lane handles rows i*4+qk, cols 4*colq..+3
        #pragma unroll
        for (int i = 0; i < 4; ++i) {
            const int r16 = i * 4 + qk;
            const int row = m0 + mt * 16 + r16;
            const int cc4 = 4 * colq;
            f32x4 v;
            v.x = Ts[r16 * 67 + cc4 + 0];
            v.y = Ts[r16 * 67 + cc4 + 1];
            v.z = Ts[r16 * 67 + cc4 + 2];
            v.w = Ts[r16 * 67 + cc4 + 3];
            if (full || (c0 + cc4 < CTOT))
                __builtin_nontemporal_store(
                    v, (f32x4*)(out + (size_t)row * CTOT + c0 + cc4));
        }
        // guard scratch reuse: reads of mt must complete before mt+1 writes
        asm volatile("s_waitcnt lgkmcnt(0)" ::: "memory");
    }
}

extern "C" void kernel_launch(void* const* d_in, const int* in_sizes, int n_in,
                              void* d_out, int out_size, void* d_ws, size_t ws_size,
                              hipStream_t stream) {
    const float* x     = (const float*)d_in[0];
    const int*   label = (const int*)d_in[1];
    const float* w     = (const float*)d_in[2];
    float* out = (float*)d_out;

    // workspace layout: target (2 KB) + exbF (512 KB)
    float*    target = (float*)d_ws;
    ushort_t* exbF   = (ushort_t*)((char*)d_ws + 2048);

    arc_prep<<<512, 256, 0, stream>>>(x, label, w, target, exbF);
    arc_fused<<<CPAD / BNF, 512, 0, stream>>>(exbF, w, label, target, out);
}